// Round 2
// baseline (268.713 us; speedup 1.0000x reference)
//
#include <hip/hip_runtime.h>
#include <math.h>

#define PUPIL 256
#define OUT_DIM 64
#define N_BINS 8
#define BATCH 16

__constant__ int PHASE_NS_C[N_BINS] = {1024, 988, 952, 918, 886, 856, 828, 802};

// PSF[u,v] = | sum_{y,x} P[y,x] W[y,ku] W[x,kv] |^2 ; W[n,k]=e^{-2pi i (k-32) n/N}
// P = obsc * exp(i*2pi/lambda * opd). Centered-pad phase prefactor killed by |.|^2.
// Stage1: over x (256->64), Stage2: over y (256->64), then |.|^2, norm, SED-sum.

__global__ void twiddle_init(float2* __restrict__ twid) {
  int idx = blockIdx.x * 256 + threadIdx.x;       // 8*256*64
  int kv  = idx & 63;
  int x   = (idx >> 6) & 255;
  int bin = idx >> 14;
  int N = PHASE_NS_C[bin];
  int k = kv - 32;
  int m = (k * x) % N;
  if (m < 0) m += N;
  float ang = -6.283185307179586f * (float)m / (float)N;
  float s, c;
  sincosf(ang, &s, &c);
  twid[idx] = make_float2(c, s);
}

// Stage 1: G[b][bin][y][kv] = sum_x P[y][x] * W[x][kv]
// grid (8 ychunks of 32, 8 bins, 16 b) = 1024 blocks; 256 thr; 2y x 4kv/thread.
__global__ __launch_bounds__(256, 4) void stage1(
    const float* __restrict__ opd, const float* __restrict__ obsc,
    const float* __restrict__ lambdas, const float2* __restrict__ twid,
    float2* __restrict__ G)
{
  const int tid = threadIdx.x;
  const int ybase = blockIdx.x * 32, bin = blockIdx.y, b = blockIdx.z;
  const float w0 = 6.283185307179586f / lambdas[bin];

  __shared__ float2 Pt[32][34];   // [x][y] (c,s); stride 34 keeps 16B align + kills 32-way
  __shared__ float4 Tt4[32][32];  // [x][kv-pair] (c0,s0,c1,s1)

  const int ty = tid >> 4, tkv = tid & 15;
  float ar[2][4] = {{0.f}}, ai[2][4] = {{0.f}};
  const float4* tw4 = (const float4*)twid;

  for (int xc = 0; xc < 8; ++xc) {
    const int xbase = xc * 32;
    {
      const int xl = tid & 31, y0 = tid >> 5;
      #pragma unroll
      for (int i = 0; i < 4; ++i) {
        const int yl = y0 + i * 8;
        const int y = ybase + yl, x = xbase + xl;
        const float o  = obsc[y * PUPIL + x];
        const float od = opd[(b * PUPIL + y) * PUPIL + x];
        float s, c;
        __sincosf(w0 * od, &s, &c);
        Pt[xl][yl] = make_float2(c * o, s * o);
      }
      const int p2 = tid & 31, xr0 = tid >> 5;
      #pragma unroll
      for (int i = 0; i < 4; ++i) {
        const int xr = xr0 + i * 8;
        Tt4[xr][p2] = tw4[(bin * 256 + xbase + xr) * 32 + p2];
      }
    }
    __syncthreads();
    #pragma unroll
    for (int xl = 0; xl < 32; ++xl) {
      const float4 p   = *reinterpret_cast<const float4*>(&Pt[xl][ty * 2]); // y0:(x,y) y1:(z,w)
      const float4 t01 = Tt4[xl][tkv];        // kv = 2tkv, 2tkv+1
      const float4 t23 = Tt4[xl][tkv + 16];   // kv = 32+2tkv, 32+2tkv+1
      #pragma unroll
      for (int i = 0; i < 2; ++i) {
        const float pr = i ? p.z : p.x;
        const float pi = i ? p.w : p.y;
        ar[i][0] += pr * t01.x - pi * t01.y;  ai[i][0] += pr * t01.y + pi * t01.x;
        ar[i][1] += pr * t01.z - pi * t01.w;  ai[i][1] += pr * t01.w + pi * t01.z;
        ar[i][2] += pr * t23.x - pi * t23.y;  ai[i][2] += pr * t23.y + pi * t23.x;
        ar[i][3] += pr * t23.z - pi * t23.w;  ai[i][3] += pr * t23.w + pi * t23.z;
      }
    }
    __syncthreads();
  }
  float4* G4 = (float4*)G;
  #pragma unroll
  for (int i = 0; i < 2; ++i) {
    const int y = ybase + ty * 2 + i;
    const size_t row = ((size_t)(b * N_BINS + bin) * 256 + y) * 32; // float4 units
    G4[row + tkv]      = make_float4(ar[i][0], ai[i][0], ar[i][1], ai[i][1]);
    G4[row + 16 + tkv] = make_float4(ar[i][2], ai[i][2], ar[i][3], ai[i][3]);
  }
}

// Stage 2: H[ku][kv] = sum_y W[y][ku]*G[y][kv]; |H|^2 + per-block partial sum.
// grid (4 kuchunks of 16, 8 bins, 16 b) = 512 blocks; 1ku x 4kv per thread.
__global__ __launch_bounds__(256, 2) void stage2(
    const float2* __restrict__ G, const float2* __restrict__ twid,
    float* __restrict__ psf_raw, float* __restrict__ sums)
{
  const int tid = threadIdx.x;
  const int uchunk = blockIdx.x, bin = blockIdx.y, b = blockIdx.z;

  __shared__ float2 Wt[32][17];   // [y][ku_local]
  __shared__ float4 Gt4[32][32];  // [y][kv-pair]
  __shared__ float red[4];

  const int tu = tid >> 4, tkv = tid & 15;
  const int ku = uchunk * 16 + tu;
  float ar[4] = {0.f, 0.f, 0.f, 0.f}, ai[4] = {0.f, 0.f, 0.f, 0.f};
  const float4* G4 = (const float4*)G;

  for (int yc = 0; yc < 8; ++yc) {
    const int ybase = yc * 32;
    {
      const int kl = tid & 15, yr = tid >> 4;
      Wt[yr][kl]      = twid[(bin * 256 + ybase + yr) * 64 + uchunk * 16 + kl];
      Wt[yr + 16][kl] = twid[(bin * 256 + ybase + yr + 16) * 64 + uchunk * 16 + kl];
      const int p2 = tid & 31, yr0 = tid >> 5;
      #pragma unroll
      for (int i = 0; i < 4; ++i) {
        const int yy = yr0 + i * 8;
        Gt4[yy][p2] = G4[((size_t)(b * N_BINS + bin) * 256 + ybase + yy) * 32 + p2];
      }
    }
    __syncthreads();
    #pragma unroll
    for (int yl = 0; yl < 32; ++yl) {
      const float2 w   = Wt[yl][tu];
      const float4 g01 = Gt4[yl][tkv];
      const float4 g23 = Gt4[yl][tkv + 16];
      ar[0] += w.x * g01.x - w.y * g01.y;  ai[0] += w.x * g01.y + w.y * g01.x;
      ar[1] += w.x * g01.z - w.y * g01.w;  ai[1] += w.x * g01.w + w.y * g01.z;
      ar[2] += w.x * g23.x - w.y * g23.y;  ai[2] += w.x * g23.y + w.y * g23.x;
      ar[3] += w.x * g23.z - w.y * g23.w;  ai[3] += w.x * g23.w + w.y * g23.z;
    }
    __syncthreads();
  }

  float pv[4];
  float lsum = 0.f;
  #pragma unroll
  for (int j = 0; j < 4; ++j) {
    pv[j] = ar[j] * ar[j] + ai[j] * ai[j];
    lsum += pv[j];
  }
  #pragma unroll
  for (int off = 32; off > 0; off >>= 1) lsum += __shfl_down(lsum, off);
  const int lane = tid & 63, wid = tid >> 6;
  if (lane == 0) red[wid] = lsum;
  __syncthreads();
  if (tid == 0)
    sums[(b * N_BINS + bin) * 4 + uchunk] = red[0] + red[1] + red[2] + red[3];

  const size_t base = (size_t)(b * N_BINS + bin) * 4096 + (size_t)ku * 64;
  *(float2*)&psf_raw[base + tkv * 2]      = make_float2(pv[0], pv[1]);
  *(float2*)&psf_raw[base + 32 + tkv * 2] = make_float2(pv[2], pv[3]);
}

// scales[(b,bin)] = sed[bin] / S[b][bin]
__global__ void finalize_scales(const float* __restrict__ sums,
                                const float* __restrict__ sed,
                                float* __restrict__ scales) {
  int i = threadIdx.x;  // 128 = b*8+bin
  if (i < BATCH * N_BINS) {
    float S = sums[i * 4] + sums[i * 4 + 1] + sums[i * 4 + 2] + sums[i * 4 + 3];
    scales[i] = sed[i & 7] / S;
  }
}

__global__ void combine(const float* __restrict__ psf_raw,
                        const float* __restrict__ scales,
                        float* __restrict__ out) {
  int idx = blockIdx.x * 256 + threadIdx.x;   // 16*64*64
  int b = idx >> 12, p = idx & 4095;
  float acc = 0.f;
  #pragma unroll
  for (int bin = 0; bin < N_BINS; ++bin)
    acc += scales[b * N_BINS + bin] * psf_raw[(size_t)(b * N_BINS + bin) * 4096 + p];
  out[idx] = acc;
}

extern "C" void kernel_launch(void* const* d_in, const int* in_sizes, int n_in,
                              void* d_out, int out_size, void* d_ws, size_t ws_size,
                              hipStream_t stream) {
  const float* opd     = (const float*)d_in[0];
  const float* obsc    = (const float*)d_in[1];
  const float* lambdas = (const float*)d_in[2];
  const float* sed     = (const float*)d_in[3];
  float* out = (float*)d_out;

  // ws: twid 1MB | G 16MB | psf_raw 2MB | sums 2KB | scales 512B
  float2* twid    = (float2*)d_ws;
  float2* G       = twid + (size_t)N_BINS * 256 * 64;
  float*  psf_raw = (float*)(G + (size_t)BATCH * N_BINS * 256 * 64);
  float*  sums    = psf_raw + (size_t)BATCH * N_BINS * 4096;
  float*  scales  = sums + (size_t)BATCH * N_BINS * 4;

  twiddle_init<<<512, 256, 0, stream>>>(twid);
  stage1<<<dim3(8, N_BINS, BATCH), 256, 0, stream>>>(opd, obsc, lambdas, twid, G);
  stage2<<<dim3(4, N_BINS, BATCH), 256, 0, stream>>>(G, twid, psf_raw, sums);
  finalize_scales<<<1, 128, 0, stream>>>(sums, sed, scales);
  combine<<<256, 256, 0, stream>>>(psf_raw, scales, out);
}

// Round 3
// 220.379 us; speedup vs baseline: 1.2193x; 1.2193x over previous
//
#include <hip/hip_runtime.h>
#include <math.h>

#define PUPIL 256
#define OUT_DIM 64
#define N_BINS 8
#define BATCH 16

__constant__ int PHASE_NS_C[N_BINS] = {1024, 988, 952, 918, 886, 856, 828, 802};

// PSF[u,v] = | sum_{y,x} P[y,x] W[y,ku] W[x,kv] |^2 ; W[n,k]=e^{-2pi i (k-32) n/N}
// P = obsc * exp(i*2pi/lambda * opd). Centered-pad phase prefactor killed by |.|^2.
// Stage1 contracts x (256->64), Stage2 contracts y (256->64), then |.|^2 + norm.

__global__ void twiddle_init(float2* __restrict__ twid) {
  int idx = blockIdx.x * 256 + threadIdx.x;       // 8*256*64
  int kv  = idx & 63;
  int x   = (idx >> 6) & 255;
  int bin = idx >> 14;
  int N = PHASE_NS_C[bin];
  int k = kv - 32;
  int m = (k * x) % N;
  if (m < 0) m += N;
  float ang = -6.283185307179586f * (float)m / (float)N;
  float s, c;
  sincosf(ang, &s, &c);
  twid[idx] = make_float2(c, s);
}

// Stage 1: G[b][bin][y][kv] = sum_x P[y][x] * W[x][kv]
// grid (8 ychunks of 32, 8 bins, 16 b) = 1024 blocks; 256 thr; 2y x 4kv/thread.
__global__ __launch_bounds__(256, 4) void stage1(
    const float* __restrict__ opd, const float* __restrict__ obsc,
    const float* __restrict__ lambdas, const float2* __restrict__ twid,
    float2* __restrict__ G)
{
  const int tid = threadIdx.x;
  const int ybase = blockIdx.x * 32, bin = blockIdx.y, b = blockIdx.z;
  const float w0 = 6.283185307179586f / lambdas[bin];

  // Pc stride 33 f2: write bank-stride 2 -> 2-way (free); reads are broadcasts.
  // Tc reads Tc[xl][j*16+tkv]: 16 addrs x 8B span all 32 banks, 4-way broadcast (free).
  __shared__ float2 Pc[32][33];   // [x_local][y_local]
  __shared__ float2 Tc[32][64];   // [x_local][kv]

  const int ty = tid >> 4, tkv = tid & 15;
  float ar[2][4] = {{0.f}}, ai[2][4] = {{0.f}};

  for (int xc = 0; xc < 8; ++xc) {
    const int xbase = xc * 32;
    // P tile: 32x * 32y, lanes coalesced over x; phase on the fly
    {
      const int xl = tid & 31, y0 = tid >> 5;
      #pragma unroll
      for (int i = 0; i < 4; ++i) {
        const int yl = y0 + i * 8;
        const int y = ybase + yl, x = xbase + xl;
        const float o  = obsc[y * PUPIL + x];
        const float od = opd[(b * PUPIL + y) * PUPIL + x];
        float s, c;
        __sincosf(w0 * od, &s, &c);
        Pc[xl][yl] = make_float2(c * o, s * o);
      }
    }
    // T tile: 32x * 64kv, lanes coalesced over kv (R1's exact pattern)
    {
      const int kvl = tid & 63, xr0 = tid >> 6;
      #pragma unroll
      for (int i = 0; i < 8; ++i) {
        const int xr = xr0 + i * 4;
        Tc[xr][kvl] = twid[(bin * 256 + xbase + xr) * 64 + kvl];
      }
    }
    __syncthreads();
    for (int xl = 0; xl < 32; ++xl) {   // NOT force-unrolled (R2 spill lesson)
      const float2 t0 = Tc[xl][tkv];
      const float2 t1 = Tc[xl][16 + tkv];
      const float2 t2 = Tc[xl][32 + tkv];
      const float2 t3 = Tc[xl][48 + tkv];
      const float2 p0 = Pc[xl][ty * 2];
      const float2 p1 = Pc[xl][ty * 2 + 1];
      ar[0][0] += p0.x * t0.x - p0.y * t0.y;  ai[0][0] += p0.x * t0.y + p0.y * t0.x;
      ar[0][1] += p0.x * t1.x - p0.y * t1.y;  ai[0][1] += p0.x * t1.y + p0.y * t1.x;
      ar[0][2] += p0.x * t2.x - p0.y * t2.y;  ai[0][2] += p0.x * t2.y + p0.y * t2.x;
      ar[0][3] += p0.x * t3.x - p0.y * t3.y;  ai[0][3] += p0.x * t3.y + p0.y * t3.x;
      ar[1][0] += p1.x * t0.x - p1.y * t0.y;  ai[1][0] += p1.x * t0.y + p1.y * t0.x;
      ar[1][1] += p1.x * t1.x - p1.y * t1.y;  ai[1][1] += p1.x * t1.y + p1.y * t1.x;
      ar[1][2] += p1.x * t2.x - p1.y * t2.y;  ai[1][2] += p1.x * t2.y + p1.y * t2.x;
      ar[1][3] += p1.x * t3.x - p1.y * t3.y;  ai[1][3] += p1.x * t3.y + p1.y * t3.x;
    }
    __syncthreads();
  }
  #pragma unroll
  for (int i = 0; i < 2; ++i) {
    const int y = ybase + ty * 2 + i;
    const size_t row = ((size_t)(b * N_BINS + bin) * 256 + y) * 64;
    G[row + tkv]      = make_float2(ar[i][0], ai[i][0]);
    G[row + 16 + tkv] = make_float2(ar[i][1], ai[i][1]);
    G[row + 32 + tkv] = make_float2(ar[i][2], ai[i][2]);
    G[row + 48 + tkv] = make_float2(ar[i][3], ai[i][3]);
  }
}

// Stage 2: H[ku][kv] = sum_y W[y][ku]*G[y][kv]; |H|^2 + per-block partial sum.
// grid (4 kuchunks of 16, 8 bins, 16 b) = 512 blocks; 1ku x 4kv per thread.
__global__ __launch_bounds__(256, 4) void stage2(
    const float2* __restrict__ G, const float2* __restrict__ twid,
    float* __restrict__ psf_raw, float* __restrict__ sums)
{
  const int tid = threadIdx.x;
  const int uchunk = blockIdx.x, bin = blockIdx.y, b = blockIdx.z;

  __shared__ float2 Wt[32][17];   // [y_local][ku_local]
  __shared__ float2 Gt[32][64];   // [y_local][kv]
  __shared__ float red[4];

  const int tu = tid >> 4, tkv = tid & 15;
  const int ku = uchunk * 16 + tu;
  float ar[4] = {0.f, 0.f, 0.f, 0.f}, ai[4] = {0.f, 0.f, 0.f, 0.f};

  for (int yc = 0; yc < 8; ++yc) {
    const int ybase = yc * 32;
    {
      const int kl = tid & 15, yr = tid >> 4;
      Wt[yr][kl]      = twid[(bin * 256 + ybase + yr) * 64 + uchunk * 16 + kl];
      Wt[yr + 16][kl] = twid[(bin * 256 + ybase + yr + 16) * 64 + uchunk * 16 + kl];
      const int kvl = tid & 63, yr0 = tid >> 6;
      #pragma unroll
      for (int i = 0; i < 8; ++i) {
        const int yy = yr0 + i * 4;
        Gt[yy][kvl] = G[((size_t)(b * N_BINS + bin) * 256 + ybase + yy) * 64 + kvl];
      }
    }
    __syncthreads();
    for (int yl = 0; yl < 32; ++yl) {
      const float2 w  = Wt[yl][tu];
      const float2 g0 = Gt[yl][tkv];
      const float2 g1 = Gt[yl][16 + tkv];
      const float2 g2 = Gt[yl][32 + tkv];
      const float2 g3 = Gt[yl][48 + tkv];
      ar[0] += w.x * g0.x - w.y * g0.y;  ai[0] += w.x * g0.y + w.y * g0.x;
      ar[1] += w.x * g1.x - w.y * g1.y;  ai[1] += w.x * g1.y + w.y * g1.x;
      ar[2] += w.x * g2.x - w.y * g2.y;  ai[2] += w.x * g2.y + w.y * g2.x;
      ar[3] += w.x * g3.x - w.y * g3.y;  ai[3] += w.x * g3.y + w.y * g3.x;
    }
    __syncthreads();
  }

  float pv[4];
  float lsum = 0.f;
  #pragma unroll
  for (int j = 0; j < 4; ++j) {
    pv[j] = ar[j] * ar[j] + ai[j] * ai[j];
    lsum += pv[j];
  }
  #pragma unroll
  for (int off = 32; off > 0; off >>= 1) lsum += __shfl_down(lsum, off);
  const int lane = tid & 63, wid = tid >> 6;
  if (lane == 0) red[wid] = lsum;
  __syncthreads();
  if (tid == 0)
    sums[(b * N_BINS + bin) * 4 + uchunk] = red[0] + red[1] + red[2] + red[3];

  const size_t base = (size_t)(b * N_BINS + bin) * 4096 + (size_t)ku * 64;
  psf_raw[base + tkv]      = pv[0];
  psf_raw[base + 16 + tkv] = pv[1];
  psf_raw[base + 32 + tkv] = pv[2];
  psf_raw[base + 48 + tkv] = pv[3];
}

__global__ void finalize_scales(const float* __restrict__ sums,
                                const float* __restrict__ sed,
                                float* __restrict__ scales) {
  int i = threadIdx.x;  // 128 = b*8+bin
  if (i < BATCH * N_BINS) {
    float S = sums[i * 4] + sums[i * 4 + 1] + sums[i * 4 + 2] + sums[i * 4 + 3];
    scales[i] = sed[i & 7] / S;
  }
}

__global__ void combine(const float* __restrict__ psf_raw,
                        const float* __restrict__ scales,
                        float* __restrict__ out) {
  int idx = blockIdx.x * 256 + threadIdx.x;   // 16*64*64
  int b = idx >> 12, p = idx & 4095;
  float acc = 0.f;
  #pragma unroll
  for (int bin = 0; bin < N_BINS; ++bin)
    acc += scales[b * N_BINS + bin] * psf_raw[(size_t)(b * N_BINS + bin) * 4096 + p];
  out[idx] = acc;
}

extern "C" void kernel_launch(void* const* d_in, const int* in_sizes, int n_in,
                              void* d_out, int out_size, void* d_ws, size_t ws_size,
                              hipStream_t stream) {
  const float* opd     = (const float*)d_in[0];
  const float* obsc    = (const float*)d_in[1];
  const float* lambdas = (const float*)d_in[2];
  const float* sed     = (const float*)d_in[3];
  float* out = (float*)d_out;

  // ws: twid 1MB | G 16MB | psf_raw 2MB | sums 2KB | scales 512B
  float2* twid    = (float2*)d_ws;
  float2* G       = twid + (size_t)N_BINS * 256 * 64;
  float*  psf_raw = (float*)(G + (size_t)BATCH * N_BINS * 256 * 64);
  float*  sums    = psf_raw + (size_t)BATCH * N_BINS * 4096;
  float*  scales  = sums + (size_t)BATCH * N_BINS * 4;

  twiddle_init<<<512, 256, 0, stream>>>(twid);
  stage1<<<dim3(8, N_BINS, BATCH), 256, 0, stream>>>(opd, obsc, lambdas, twid, G);
  stage2<<<dim3(4, N_BINS, BATCH), 256, 0, stream>>>(G, twid, psf_raw, sums);
  finalize_scales<<<1, 128, 0, stream>>>(sums, sed, scales);
  combine<<<256, 256, 0, stream>>>(psf_raw, scales, out);
}

// Round 4
// 89.038 us; speedup vs baseline: 3.0180x; 2.4751x over previous
//
#include <hip/hip_runtime.h>
#include <math.h>

#define PUPIL 256
#define OUT_DIM 64
#define N_BINS 8
#define BATCH 16

__constant__ int PHASE_NS_C[N_BINS] = {1024, 988, 952, 918, 886, 856, 828, 802};

typedef short bf16x8 __attribute__((ext_vector_type(8)));
typedef float f32x4  __attribute__((ext_vector_type(4)));
typedef int   i32x4  __attribute__((ext_vector_type(4)));

#define MFMA16(a, b, c) __builtin_amdgcn_mfma_f32_16x16x32_bf16((a), (b), (c), 0, 0, 0)

__device__ __forceinline__ short f2bf(float f) {   // RNE float->bf16
  unsigned u = __float_as_uint(f);
  u += 0x7FFFu + ((u >> 16) & 1u);
  return (short)(u >> 16);
}

__device__ __forceinline__ bf16x8 neg8(bf16x8 v) { // flip sign bits of 8 bf16
  i32x4 t = __builtin_bit_cast(i32x4, v);
  t ^= (int)0x80008000;
  return __builtin_bit_cast(bf16x8, t);
}

// ---------------------------------------------------------------------------
// PSF[u,v] = | sum_{y,x} P[y,x] W[y,u] W[x,v] |^2 ; W[n,k]=e^{-2pi i (k-32) n/N}
// Stage1: G^T = W^T . P^T  (A = W_t[kv][x], B = P[y][x] rows)  -> G_t[kv][y]
// Stage2: H^T = G^T . W    (A = G_t[kv][y], B = W_t[ku][y] rows)
// MFMA 16x16x32 bf16 layouts: A[m=lane&15][k=quad*8+j] (16B contig),
// B-frag = B^T row (same shape), D: col=lane&15, row=quad*4+reg.
// ---------------------------------------------------------------------------

// W_t[bin][k=64][n=256] bf16, value = e^{-2pi i (k-32) n / N}
__global__ void wprep(short* __restrict__ Wr_t, short* __restrict__ Wi_t) {
  int idx = blockIdx.x * 256 + threadIdx.x;   // 8*64*256 = 131072
  int n   = idx & 255;
  int k   = (idx >> 8) & 63;
  int bin = idx >> 14;
  int N = PHASE_NS_C[bin];
  int m = ((k - 32) * n) % N;
  if (m < 0) m += N;
  float ang = -6.283185307179586f * (float)m / (float)N;
  float s, c;
  sincosf(ang, &s, &c);
  Wr_t[idx] = f2bf(c);
  Wi_t[idx] = f2bf(s);
}

// Stage1: per block: (b,bin), one 64-y slab; M=64 kv (4 waves x 16), N=64 y,
// K=256 x in 8 chunks of 32. P chunk generated into LDS once, shared by waves.
__global__ __launch_bounds__(256, 2) void stage1(
    const float* __restrict__ opd, const float* __restrict__ obsc,
    const float* __restrict__ lambdas,
    const short* __restrict__ Wr_t, const short* __restrict__ Wi_t,
    short* __restrict__ Gr_t, short* __restrict__ Gi_t)
{
  const int tid = threadIdx.x;
  const int yb = blockIdx.x, bin = blockIdx.y, b = blockIdx.z;
  const int bb = b * N_BINS + bin;
  const float w0 = 6.283185307179586f / lambdas[bin];

  __shared__ short Pr[64 * 32], Pi[64 * 32];   // [y_local][x_local] bf16

  const int wave = tid >> 6, lane = tid & 63;
  const int lr = lane & 15, lq = lane >> 4;

  f32x4 accR[4], accI[4];
  #pragma unroll
  for (int t = 0; t < 4; ++t) { accR[t] = (f32x4)0.0f; accI[t] = (f32x4)0.0f; }

  // P-generation indices: thread -> (y row, 8-x chunk)
  const int py = tid >> 2;            // 0..63
  const int px = (tid & 3) * 8;       // 0,8,16,24
  const float* opdrow = opd + ((size_t)b * PUPIL + (yb * 64 + py)) * PUPIL;
  const float* obsrow = obsc + (size_t)(yb * 64 + py) * PUPIL;

  const short* wrb = Wr_t + ((size_t)bin * 64 + wave * 16 + lr) * 256 + lq * 8;
  const short* wib = Wi_t + ((size_t)bin * 64 + wave * 16 + lr) * 256 + lq * 8;

  for (int xc = 0; xc < 8; ++xc) {
    const int xbase = xc * 32;
    // generate this chunk's P tile (64y x 32x)
    float od[8], ob[8];
    *(float4*)&od[0] = *(const float4*)(opdrow + xbase + px);
    *(float4*)&od[4] = *(const float4*)(opdrow + xbase + px + 4);
    *(float4*)&ob[0] = *(const float4*)(obsrow + xbase + px);
    *(float4*)&ob[4] = *(const float4*)(obsrow + xbase + px + 4);
    bf16x8 vr, vi;
    #pragma unroll
    for (int j = 0; j < 8; ++j) {
      float s, c;
      __sincosf(w0 * od[j], &s, &c);
      vr[j] = f2bf(c * ob[j]);
      vi[j] = f2bf(s * ob[j]);
    }
    __syncthreads();                       // protect previous chunk's reads
    *(bf16x8*)&Pr[py * 32 + px] = vr;      // contiguous 16B/lane, conflict-free
    *(bf16x8*)&Pi[py * 32 + px] = vi;
    // A-frags (global, L1/L2-hot) issued before barrier; drained by it
    const bf16x8 wr  = *(const bf16x8*)(wrb + xbase);
    const bf16x8 wi  = *(const bf16x8*)(wib + xbase);
    const bf16x8 nwi = neg8(wi);
    __syncthreads();

    #pragma unroll
    for (int t = 0; t < 4; ++t) {
      const bf16x8 pr = *(const bf16x8*)&Pr[(t * 16 + lr) * 32 + lq * 8];
      const bf16x8 pi = *(const bf16x8*)&Pi[(t * 16 + lr) * 32 + lq * 8];
      accR[t] = MFMA16(wr,  pr, accR[t]);   // + Wr*Pr
      accR[t] = MFMA16(nwi, pi, accR[t]);   // - Wi*Pi
      accI[t] = MFMA16(wr,  pi, accI[t]);   // + Wr*Pi
      accI[t] = MFMA16(wi,  pr, accI[t]);   // + Wi*Pr
    }
  }

  // store G_t[bb][kv][y] bf16; D: row(kv-local)=lq*4+r, col(y-local)=lr
  #pragma unroll
  for (int t = 0; t < 4; ++t) {
    const int yg = yb * 64 + t * 16 + lr;
    #pragma unroll
    for (int r = 0; r < 4; ++r) {
      const int kv = wave * 16 + lq * 4 + r;
      const size_t o = ((size_t)bb * 64 + kv) * 256 + yg;
      Gr_t[o] = f2bf(accR[t][r]);
      Gi_t[o] = f2bf(accI[t][r]);
    }
  }
}

// Stage2: one block per (b,bin): M=64 kv (4 waves x 16), N=64 ku, K=256 y.
// |H|^2, block-wide sum, scale by sed/S, store scaled psf.
__global__ __launch_bounds__(256, 2) void stage2(
    const short* __restrict__ Wr_t, const short* __restrict__ Wi_t,
    const short* __restrict__ Gr_t, const short* __restrict__ Gi_t,
    const float* __restrict__ sed, float* __restrict__ psf_s)
{
  const int tid = threadIdx.x;
  const int bin = blockIdx.x, b = blockIdx.y;
  const int bb = b * N_BINS + bin;

  __shared__ float red[4];

  const int wave = tid >> 6, lane = tid & 63;
  const int lr = lane & 15, lq = lane >> 4;

  f32x4 hr[4], hi[4];
  #pragma unroll
  for (int t = 0; t < 4; ++t) { hr[t] = (f32x4)0.0f; hi[t] = (f32x4)0.0f; }

  const short* grb = Gr_t + ((size_t)bb * 64 + wave * 16 + lr) * 256 + lq * 8;
  const short* gib = Gi_t + ((size_t)bb * 64 + wave * 16 + lr) * 256 + lq * 8;

  for (int yc = 0; yc < 8; ++yc) {
    const int ybase = yc * 32;
    const bf16x8 gr  = *(const bf16x8*)(grb + ybase);
    const bf16x8 gi  = *(const bf16x8*)(gib + ybase);
    const bf16x8 ngi = neg8(gi);
    #pragma unroll
    for (int t = 0; t < 4; ++t) {
      const size_t wo = ((size_t)bin * 64 + t * 16 + lr) * 256 + ybase + lq * 8;
      const bf16x8 wr = *(const bf16x8*)(Wr_t + wo);
      const bf16x8 wi = *(const bf16x8*)(Wi_t + wo);
      hr[t] = MFMA16(gr,  wr, hr[t]);   // + Gr*Wr
      hr[t] = MFMA16(ngi, wi, hr[t]);   // - Gi*Wi
      hi[t] = MFMA16(gr,  wi, hi[t]);   // + Gr*Wi
      hi[t] = MFMA16(gi,  wr, hi[t]);   // + Gi*Wr
    }
  }

  float pv[4][4];
  float lsum = 0.f;
  #pragma unroll
  for (int t = 0; t < 4; ++t)
    #pragma unroll
    for (int r = 0; r < 4; ++r) {
      pv[t][r] = hr[t][r] * hr[t][r] + hi[t][r] * hi[t][r];
      lsum += pv[t][r];
    }
  #pragma unroll
  for (int off = 32; off > 0; off >>= 1) lsum += __shfl_down(lsum, off);
  if (lane == 0) red[wave] = lsum;
  __syncthreads();
  const float S = red[0] + red[1] + red[2] + red[3];
  const float scale = sed[bin] / S;

  // D: row = kv-local = lq*4+r -> v ; col = ku-local = lr -> u
  #pragma unroll
  for (int t = 0; t < 4; ++t) {
    const int u = t * 16 + lr;
    #pragma unroll
    for (int r = 0; r < 4; ++r) {
      const int v = wave * 16 + lq * 4 + r;
      psf_s[(size_t)bb * 4096 + u * 64 + v] = pv[t][r] * scale;
    }
  }
}

__global__ void combine(const float* __restrict__ psf_s, float* __restrict__ out) {
  int idx = blockIdx.x * 256 + threadIdx.x;   // 16*64*64
  int b = idx >> 12, p = idx & 4095;
  float acc = 0.f;
  #pragma unroll
  for (int bin = 0; bin < N_BINS; ++bin)
    acc += psf_s[(size_t)(b * N_BINS + bin) * 4096 + p];
  out[idx] = acc;
}

extern "C" void kernel_launch(void* const* d_in, const int* in_sizes, int n_in,
                              void* d_out, int out_size, void* d_ws, size_t ws_size,
                              hipStream_t stream) {
  const float* opd     = (const float*)d_in[0];
  const float* obsc    = (const float*)d_in[1];
  const float* lambdas = (const float*)d_in[2];
  const float* sed     = (const float*)d_in[3];
  float* out = (float*)d_out;

  // ws: Wr_t 256KB | Wi_t 256KB | Gr_t 4.2MB | Gi_t 4.2MB | psf_s 2.1MB
  short* Wr_t = (short*)d_ws;
  short* Wi_t = Wr_t + (size_t)N_BINS * 64 * 256;
  short* Gr_t = Wi_t + (size_t)N_BINS * 64 * 256;
  short* Gi_t = Gr_t + (size_t)BATCH * N_BINS * 64 * 256;
  float* psf_s = (float*)(Gi_t + (size_t)BATCH * N_BINS * 64 * 256);

  wprep<<<512, 256, 0, stream>>>(Wr_t, Wi_t);
  stage1<<<dim3(4, N_BINS, BATCH), 256, 0, stream>>>(opd, obsc, lambdas,
                                                     Wr_t, Wi_t, Gr_t, Gi_t);
  stage2<<<dim3(N_BINS, BATCH), 256, 0, stream>>>(Wr_t, Wi_t, Gr_t, Gi_t,
                                                  sed, psf_s);
  combine<<<256, 256, 0, stream>>>(psf_s, out);
}

// Round 5
// 84.977 us; speedup vs baseline: 3.1622x; 1.0478x over previous
//
#include <hip/hip_runtime.h>
#include <math.h>

#define PUPIL 256
#define N_BINS 8
#define BATCH 16

__constant__ int PHASE_NS_C[N_BINS] = {1024, 988, 952, 918, 886, 856, 828, 802};

typedef short bf16x8 __attribute__((ext_vector_type(8)));
typedef float f32x4  __attribute__((ext_vector_type(4)));
typedef int   i32x4  __attribute__((ext_vector_type(4)));

#define MFMA16(a, b, c) __builtin_amdgcn_mfma_f32_16x16x32_bf16((a), (b), (c), 0, 0, 0)

__device__ __forceinline__ short f2bf(float f) {   // RNE float->bf16
  unsigned u = __float_as_uint(f);
  u += 0x7FFFu + ((u >> 16) & 1u);
  return (short)(u >> 16);
}
__device__ __forceinline__ bf16x8 neg8(bf16x8 v) {
  i32x4 t = __builtin_bit_cast(i32x4, v);
  t ^= (int)0x80008000;
  return __builtin_bit_cast(bf16x8, t);
}

// ---------------------------------------------------------------------------
// PSF[u,v] = | sum_{y,x} P[y,x] W[y,u] W[x,v] |^2 ; W[n,k]=e^{-2pi i (k-32) n/N}
// kv-split fusion: G^T row kv and H^T row kv depend only on their own kv, so
// each block owns a 32-kv half of one (b,bin): stage1 (contract x) -> G in
// LDS -> stage2 (contract y) -> |H|^2 + partial sum. combine scales by
// sed/(S0+S1) and sums bins.
// MFMA 16x16x32 bf16 (verified R4): A[m=lane&15][k=quad*8+j] 16B contig,
// B-frag = B^T row, D: col=lane&15, row=quad*4+reg.
// ---------------------------------------------------------------------------

// W_t[bin][k=64][n=256] bf16
__global__ void wprep(short* __restrict__ Wr_t, short* __restrict__ Wi_t) {
  int idx = blockIdx.x * 256 + threadIdx.x;   // 131072
  int n   = idx & 255;
  int k   = (idx >> 8) & 63;
  int bin = idx >> 14;
  int N = PHASE_NS_C[bin];
  int m = ((k - 32) * n) % N;
  if (m < 0) m += N;
  float ang = -6.283185307179586f * (float)m / (float)N;
  float s, c;
  sincosf(ang, &s, &c);
  Wr_t[idx] = f2bf(c);
  Wi_t[idx] = f2bf(s);
}

// grid (2 khalf, 8 bin, 16 b) = 256 blocks, 256 threads (4 waves)
__global__ __launch_bounds__(256, 1) void fused(
    const float* __restrict__ opd, const float* __restrict__ obsc,
    const float* __restrict__ lambdas,
    const short* __restrict__ Wr_t, const short* __restrict__ Wi_t,
    float* __restrict__ psf_raw, float* __restrict__ sums)
{
  const int tid = threadIdx.x;
  const int khalf = blockIdx.x, bin = blockIdx.y, b = blockIdx.z;
  const int bb = b * N_BINS + bin;
  const float w0 = 6.283185307179586f / lambdas[bin];

  __shared__ short Pr[256 * 40], Pi[256 * 40];  // [y][x_chunk32] pitch 40 (banks)
  __shared__ short Gr[32 * 264], Gi[32 * 264];  // [kv_local][y] pitch 264
  __shared__ float pvbuf[64 * 33];              // transpose buffer, pitch 33
  __shared__ float red[4];

  const int wave = tid >> 6, lane = tid & 63;
  const int lr = lane & 15, lq = lane >> 4;

  // ---------------- stage 1: G^T[32 kv][256 y], K = x ----------------
  f32x4 aR[2][4], aI[2][4];
  #pragma unroll
  for (int m = 0; m < 2; ++m)
    #pragma unroll
    for (int t = 0; t < 4; ++t) { aR[m][t] = (f32x4)0.0f; aI[m][t] = (f32x4)0.0f; }

  const int gy0 = tid >> 2;          // 0..63
  const int gx  = (tid & 3) * 8;     // 0,8,16,24
  const short* wr0 = Wr_t + ((size_t)bin * 64 + khalf * 32 + lr) * 256 + lq * 8;
  const short* wi0 = Wi_t + ((size_t)bin * 64 + khalf * 32 + lr) * 256 + lq * 8;

  for (int xc = 0; xc < 8; ++xc) {
    const int xb = xc * 32;
    // generate P chunk [256 y][32 x]
    bf16x8 vr[4], vi[4];
    #pragma unroll
    for (int i = 0; i < 4; ++i) {
      const int y = gy0 + i * 64;
      const float* orow = opd + ((size_t)b * PUPIL + y) * PUPIL + xb + gx;
      const float* brow = obsc + (size_t)y * PUPIL + xb + gx;
      float od[8], ob[8];
      *(float4*)&od[0] = *(const float4*)orow;
      *(float4*)&od[4] = *(const float4*)(orow + 4);
      *(float4*)&ob[0] = *(const float4*)brow;
      *(float4*)&ob[4] = *(const float4*)(brow + 4);
      #pragma unroll
      for (int j = 0; j < 8; ++j) {
        float s, c;
        __sincosf(w0 * od[j], &s, &c);
        vr[i][j] = f2bf(c * ob[j]);
        vi[i][j] = f2bf(s * ob[j]);
      }
    }
    __syncthreads();                 // previous chunk's P reads complete
    #pragma unroll
    for (int i = 0; i < 4; ++i) {
      const int y = gy0 + i * 64;
      *(bf16x8*)&Pr[y * 40 + gx] = vr[i];
      *(bf16x8*)&Pi[y * 40 + gx] = vi[i];
    }
    const bf16x8 w_r0  = *(const bf16x8*)(wr0 + xb);
    const bf16x8 w_r1  = *(const bf16x8*)(wr0 + 16 * 256 + xb);
    const bf16x8 w_i0  = *(const bf16x8*)(wi0 + xb);
    const bf16x8 w_i1  = *(const bf16x8*)(wi0 + 16 * 256 + xb);
    const bf16x8 nw_i0 = neg8(w_i0);
    const bf16x8 nw_i1 = neg8(w_i1);
    __syncthreads();                 // P chunk visible

    for (int t = 0; t < 4; ++t) {    // not force-unrolled (R2 spill lesson)
      const int y = wave * 64 + t * 16 + lr;
      const bf16x8 pr = *(const bf16x8*)&Pr[y * 40 + lq * 8];
      const bf16x8 pi = *(const bf16x8*)&Pi[y * 40 + lq * 8];
      aR[0][t] = MFMA16(w_r0,  pr, aR[0][t]);
      aR[0][t] = MFMA16(nw_i0, pi, aR[0][t]);
      aI[0][t] = MFMA16(w_r0,  pi, aI[0][t]);
      aI[0][t] = MFMA16(w_i0,  pr, aI[0][t]);
      aR[1][t] = MFMA16(w_r1,  pr, aR[1][t]);
      aR[1][t] = MFMA16(nw_i1, pi, aR[1][t]);
      aI[1][t] = MFMA16(w_r1,  pi, aI[1][t]);
      aI[1][t] = MFMA16(w_i1,  pr, aI[1][t]);
    }
  }

  // write G^T to LDS (bf16); D: row(lq*4+r)=kv-local, col(lr)=y-local
  #pragma unroll
  for (int m = 0; m < 2; ++m)
    #pragma unroll
    for (int t = 0; t < 4; ++t) {
      const int y = wave * 64 + t * 16 + lr;
      #pragma unroll
      for (int r = 0; r < 4; ++r) {
        const int kvl = m * 16 + lq * 4 + r;
        Gr[kvl * 264 + y] = f2bf(aR[m][t][r]);
        Gi[kvl * 264 + y] = f2bf(aI[m][t][r]);
      }
    }
  __syncthreads();

  // ---------------- stage 2: H^T[32 kv][64 ku], K = y ----------------
  f32x4 hR[2], hI[2];
  hR[0] = (f32x4)0.0f; hR[1] = (f32x4)0.0f;
  hI[0] = (f32x4)0.0f; hI[1] = (f32x4)0.0f;

  for (int yc = 0; yc < 8; ++yc) {
    const int yb2 = yc * 32;
    const size_t wo = ((size_t)bin * 64 + wave * 16 + lr) * 256 + yb2 + lq * 8;
    const bf16x8 w_r = *(const bf16x8*)(Wr_t + wo);   // B-frag: n=ku
    const bf16x8 w_i = *(const bf16x8*)(Wi_t + wo);
    #pragma unroll
    for (int m = 0; m < 2; ++m) {
      const bf16x8 g_r = *(const bf16x8*)&Gr[(m * 16 + lr) * 264 + yb2 + lq * 8];
      const bf16x8 g_i = *(const bf16x8*)&Gi[(m * 16 + lr) * 264 + yb2 + lq * 8];
      const bf16x8 ng_i = neg8(g_i);
      hR[m] = MFMA16(g_r,  w_r, hR[m]);
      hR[m] = MFMA16(ng_i, w_i, hR[m]);
      hI[m] = MFMA16(g_r,  w_i, hI[m]);
      hI[m] = MFMA16(g_i,  w_r, hI[m]);
    }
  }

  // |H|^2, block partial sum, transpose via LDS, coalesced store
  float pv[2][4];
  float lsum = 0.f;
  #pragma unroll
  for (int m = 0; m < 2; ++m)
    #pragma unroll
    for (int r = 0; r < 4; ++r) {
      pv[m][r] = hR[m][r] * hR[m][r] + hI[m][r] * hI[m][r];
      lsum += pv[m][r];
    }
  #pragma unroll
  for (int off = 32; off > 0; off >>= 1) lsum += __shfl_down(lsum, off);
  if (lane == 0) red[wave] = lsum;

  const int u = wave * 16 + lr;                 // D col -> ku
  #pragma unroll
  for (int m = 0; m < 2; ++m)
    #pragma unroll
    for (int r = 0; r < 4; ++r)
      pvbuf[u * 33 + m * 16 + lq * 4 + r] = pv[m][r];
  __syncthreads();

  if (tid == 0)
    sums[bb * 2 + khalf] = red[0] + red[1] + red[2] + red[3];

  #pragma unroll
  for (int k2 = 0; k2 < 8; ++k2) {
    const int i = tid + k2 * 256;               // 0..2047
    const int uu = i >> 5, vl = i & 31;
    psf_raw[(size_t)bb * 4096 + uu * 64 + khalf * 32 + vl] = pvbuf[uu * 33 + vl];
  }
}

// combine: scale = sed[bin]/(S0+S1); out = sum_bin scale*pv. 256 blocks.
__global__ void combine(const float* __restrict__ psf_raw,
                        const float* __restrict__ sums,
                        const float* __restrict__ sed,
                        float* __restrict__ out) {
  __shared__ float sc[N_BINS];
  const int blk = blockIdx.x;
  const int b = blk >> 4;                       // 16 blocks per image
  const int px = (blk & 15) * 256 + threadIdx.x;
  if (threadIdx.x < N_BINS) {
    const int bb = b * N_BINS + threadIdx.x;
    sc[threadIdx.x] = sed[threadIdx.x] / (sums[bb * 2] + sums[bb * 2 + 1]);
  }
  __syncthreads();
  float acc = 0.f;
  #pragma unroll
  for (int bin = 0; bin < N_BINS; ++bin)
    acc += sc[bin] * psf_raw[(size_t)(b * N_BINS + bin) * 4096 + px];
  out[b * 4096 + px] = acc;
}

extern "C" void kernel_launch(void* const* d_in, const int* in_sizes, int n_in,
                              void* d_out, int out_size, void* d_ws, size_t ws_size,
                              hipStream_t stream) {
  const float* opd     = (const float*)d_in[0];
  const float* obsc    = (const float*)d_in[1];
  const float* lambdas = (const float*)d_in[2];
  const float* sed     = (const float*)d_in[3];
  float* out = (float*)d_out;

  // ws: Wr_t 256KB | Wi_t 256KB | psf_raw 2MB | sums 1KB
  short* Wr_t   = (short*)d_ws;
  short* Wi_t   = Wr_t + (size_t)N_BINS * 64 * 256;
  float* psf_raw = (float*)(Wi_t + (size_t)N_BINS * 64 * 256);
  float* sums    = psf_raw + (size_t)BATCH * N_BINS * 4096;

  wprep<<<512, 256, 0, stream>>>(Wr_t, Wi_t);
  fused<<<dim3(2, N_BINS, BATCH), 256, 0, stream>>>(opd, obsc, lambdas,
                                                    Wr_t, Wi_t, psf_raw, sums);
  combine<<<256, 256, 0, stream>>>(psf_raw, sums, sed, out);
}